// Round 4
// baseline (969.725 us; speedup 1.0000x reference)
//
#include <hip/hip_runtime.h>

// ---------------------------------------------------------------------------
// ConditionalVariationalModule: B=1024, S=256, INPUT=256, LATENT=128, HIDDEN=256
//   K1: Cq = h@(qW1[0:256]+qW1[384:640]) + qb1  -> frag-packed bf16 in pm region
//       Cp = h@pW1[0:256]                       -> slot-packed bf16 in plv region
//   K2: sequential posterior scan, 64 WGs x 16 rows, 4 waves x 4 n-tiles,
//       weights pinned in VGPRs via opaque asm, raw barriers, 3 barriers/step.
//   K3: prior MLP (z@Up + Cp -> L2 -> L3), 4 waves, M=64 batch rows, one s.
// Outputs (fp32): z | pm | plv | qm | qlv, each [B,S,128].
// ---------------------------------------------------------------------------

typedef __attribute__((ext_vector_type(8))) short bfrag8;   // 8 bf16 = 4 VGPR
typedef __attribute__((ext_vector_type(4))) float facc4;    // MFMA accum
typedef __attribute__((ext_vector_type(4))) unsigned int u32x4;

__device__ __forceinline__ unsigned short f2bf(float x) {
  unsigned int u = __float_as_uint(x);
  u = (u + 0x7fffu + ((u >> 16) & 1u)) >> 16;   // RNE
  return (unsigned short)u;
}
__device__ __forceinline__ unsigned int pk2(float a, float b) {
  return (unsigned int)f2bf(a) | ((unsigned int)f2bf(b) << 16);
}
__device__ __forceinline__ float bf2f(unsigned int lo) {
  return __uint_as_float(lo << 16);
}
__device__ __forceinline__ facc4 mfma_bf16(bfrag8 a, bfrag8 b, facc4 c) {
  return __builtin_amdgcn_mfma_f32_16x16x32_bf16(a, b, c, 0, 0, 0);
}
// Load a B-fragment and make it an opaque register value: the compiler cannot
// rematerialize the load inside the loop (value is "produced" by the asm).
__device__ __forceinline__ bfrag8 load_pin(const unsigned short* p) {
  u32x4 v = *(const u32x4*)p;
  asm volatile("" : "+v"(v));
  return __builtin_bit_cast(bfrag8, v);
}
// raw workgroup barrier: LDS ordering only, NO vmcnt(0) drain
__device__ __forceinline__ void wg_barrier() {
  asm volatile("s_waitcnt lgkmcnt(0)" ::: "memory");
  __builtin_amdgcn_sched_barrier(0);
  __builtin_amdgcn_s_barrier();
  __builtin_amdgcn_sched_barrier(0);
}
#define SWC(r, c) ((c) ^ (((r) & 8) << 1))

// ---------------------------------------------------------------------------
// Pack all 8 weight matrices into B-fragment order:
// dst[((nt*KT+kt)*64+l)*8+i] = bf16( W[kt*32+(l>>4)*8+i][nt*16+(l&15)] )
// ---------------------------------------------------------------------------
__global__ void pack_all(const float* __restrict__ qW1, const float* __restrict__ qW2,
                         const float* __restrict__ qW3, const float* __restrict__ pW1,
                         const float* __restrict__ pW2, const float* __restrict__ pW3,
                         unsigned short* __restrict__ ws) {
  int b = blockIdx.x;
  const float* src; const float* src2 = nullptr; unsigned short* dst; int KT;
  if (b < 32)       { src = qW1; src2 = qW1 + 384 * 256; dst = ws;          KT = 8; }
  else if (b < 48)  { b -= 32;  src = qW1 + 256 * 256;   dst = ws + 65536;  KT = 4; }
  else if (b < 80)  { b -= 48;  src = qW2;               dst = ws + 98304;  KT = 8; }
  else if (b < 112) { b -= 80;  src = qW3;               dst = ws + 163840; KT = 8; }
  else if (b < 144) { b -= 112; src = pW1;               dst = ws + 229376; KT = 8; }
  else if (b < 160) { b -= 144; src = pW1 + 256 * 256;   dst = ws + 294912; KT = 4; }
  else if (b < 192) { b -= 160; src = pW2;               dst = ws + 327680; KT = 8; }
  else              { b -= 192; src = pW3;               dst = ws + 393216; KT = 8; }
  int t = b * 256 + (int)threadIdx.x;
  if (t >= 16 * KT * 64) return;
  int l  = t & 63;
  int kt = (t >> 6) % KT;
  int nt = t / (64 * KT);
  int n  = nt * 16 + (l & 15);
  int k0 = kt * 32 + (l >> 4) * 8;
  unsigned int o[4];
#pragma unroll
  for (int p = 0; p < 4; ++p) {
    float a = src[(size_t)(k0 + 2 * p) * 256 + n];
    float c = src[(size_t)(k0 + 2 * p + 1) * 256 + n];
    if (src2) {
      a += src2[(size_t)(k0 + 2 * p) * 256 + n];
      c += src2[(size_t)(k0 + 2 * p + 1) * 256 + n];
    }
    o[p] = pk2(a, c);
  }
  *(uint4*)(dst + (size_t)t * 8) = make_uint4(o[0], o[1], o[2], o[3]);
}

// ---------------------------------------------------------------------------
// K1: Cq (frag-packed for k2) + Cp (slot-packed for k3). 256 thr, M=32.
// ---------------------------------------------------------------------------
__global__ __launch_bounds__(256, 2) void k1_pre(
    const float* __restrict__ enc, const unsigned short* __restrict__ wq,
    const unsigned short* __restrict__ wp, const float* __restrict__ qb1,
    unsigned short* __restrict__ cq, unsigned short* __restrict__ cp) {
  __shared__ unsigned short xl[32 * 264];
  const int bid = blockIdx.x;
  const int gp = bid >> 8, s = bid & 255;
  const int tid = threadIdx.x;
  {
    int row = tid >> 3, c0 = (tid & 7) * 32;
    const float* sp = enc + (((size_t)(gp * 32 + row) * 256 + s) * 256 + c0);
#pragma unroll
    for (int q = 0; q < 4; ++q) {
      float4 a = *(const float4*)(sp + q * 8);
      float4 b = *(const float4*)(sp + q * 8 + 4);
      *(uint4*)(&xl[row * 264 + SWC(row, c0 + q * 8)]) =
          make_uint4(pk2(a.x, a.y), pk2(a.z, a.w), pk2(b.x, b.y), pk2(b.z, b.w));
    }
  }
  __syncthreads();
  const int w = tid >> 6, l = tid & 63, lm = l & 15, lg = l >> 4;
  const int rr = lg * 4;
  const int nt[4] = {2 * w, 2 * w + 1, 2 * w + 8, 2 * w + 9};
  facc4 aq[2][4], ap[2][4];
#pragma unroll
  for (int j = 0; j < 4; ++j) {
    float bv = qb1[nt[j] * 16 + lm];
    aq[0][j] = (facc4){bv, bv, bv, bv}; aq[1][j] = aq[0][j];
    ap[0][j] = (facc4){0.f, 0.f, 0.f, 0.f}; ap[1][j] = ap[0][j];
  }
#pragma unroll
  for (int kt = 0; kt < 8; ++kt) {
    bfrag8 bq[4], bp[4];
#pragma unroll
    for (int j = 0; j < 4; ++j) {
      bq[j] = *(const bfrag8*)(wq + ((size_t)(nt[j] * 8 + kt) * 64 + l) * 8);
      bp[j] = *(const bfrag8*)(wp + ((size_t)(nt[j] * 8 + kt) * 64 + l) * 8);
    }
#pragma unroll
    for (int rt = 0; rt < 2; ++rt) {
      bfrag8 x = *(const bfrag8*)(&xl[(rt * 16 + lm) * 264 + SWC(lm, kt * 32 + lg * 8)]);
#pragma unroll
      for (int j = 0; j < 4; ++j) {
        aq[rt][j] = mfma_bf16(x, bq[j], aq[rt][j]);
        ap[rt][j] = mfma_bf16(x, bp[j], ap[rt][j]);
      }
    }
  }
#pragma unroll
  for (int rt = 0; rt < 2; ++rt) {
    size_t base = ((size_t)((gp * 2 + rt) * 256 + s)) * 512 + (size_t)tid * 2;
    ((uint4*)cq)[base + 0] =
        make_uint4(pk2(aq[rt][0][0], aq[rt][0][1]), pk2(aq[rt][0][2], aq[rt][0][3]),
                   pk2(aq[rt][2][0], aq[rt][2][1]), pk2(aq[rt][2][2], aq[rt][2][3]));
    ((uint4*)cq)[base + 1] =
        make_uint4(pk2(aq[rt][1][0], aq[rt][1][1]), pk2(aq[rt][1][2], aq[rt][1][3]),
                   pk2(aq[rt][3][0], aq[rt][3][1]), pk2(aq[rt][3][2], aq[rt][3][3]));
#pragma unroll
    for (int i = 0; i < 4; ++i) {
      int b = gp * 32 + rt * 16 + rr + i;
      ((uint2*)cp)[((size_t)b * 256 + s) * 64 + w * 16 + lm] =
          make_uint2(pk2(ap[rt][0][i], ap[rt][1][i]), pk2(ap[rt][2][i], ap[rt][3][i]));
    }
  }
}

// ---------------------------------------------------------------------------
// K2: sequential posterior scan. 64 WGs x 256 thr (4 waves, 1 wave/SIMD).
// Wave w owns nt {2w,2w+1,2w+8,2w+9}: qm cols (c0,c1) + qlv cols (c0,c1)
// -> z computed fully in-lane. Weights pinned in VGPRs (~400 total).
// ---------------------------------------------------------------------------
__global__ __launch_bounds__(256, 1) void k2_scan(
    const float* __restrict__ prevz, const float* __restrict__ eps,
    const unsigned short* __restrict__ wU, const unsigned short* __restrict__ wW2,
    const unsigned short* __restrict__ wW3,
    const float* __restrict__ qb2, const float* __restrict__ qb3,
    const unsigned short* __restrict__ cq,
    float* __restrict__ z_o, float* __restrict__ qm_o, float* __restrict__ qlv_o) {
  __shared__ unsigned short zl[16 * 136];
  __shared__ unsigned short h1[16 * 264];
  __shared__ unsigned short h2[16 * 264];
  const int g = blockIdx.x, tid = threadIdx.x;
  const int w = tid >> 6, l = tid & 63, lm = l & 15, lg = l >> 4;
  const int rr = lg * 4;
  const int nt[4] = {2 * w, 2 * w + 1, 2 * w + 8, 2 * w + 9};
  const int c0 = 32 * w + lm, c1 = c0 + 16;
  const int cc[4] = {c0, c1, 128 + c0, 128 + c1};

  bfrag8 u[4][4], w2[4][8], w3[4][8];
#pragma unroll
  for (int j = 0; j < 4; ++j) {
#pragma unroll
    for (int kt = 0; kt < 4; ++kt)
      u[j][kt] = load_pin(wU + ((size_t)(nt[j] * 4 + kt) * 64 + l) * 8);
#pragma unroll
    for (int kt = 0; kt < 8; ++kt) {
      w2[j][kt] = load_pin(wW2 + ((size_t)(nt[j] * 8 + kt) * 64 + l) * 8);
      w3[j][kt] = load_pin(wW3 + ((size_t)(nt[j] * 8 + kt) * 64 + l) * 8);
    }
  }
  const float b2[4] = {qb2[nt[0] * 16 + lm], qb2[nt[1] * 16 + lm],
                       qb2[nt[2] * 16 + lm], qb2[nt[3] * 16 + lm]};
  const float b3[4] = {qb3[nt[0] * 16 + lm], qb3[nt[1] * 16 + lm],
                       qb3[nt[2] * 16 + lm], qb3[nt[3] * 16 + lm]};
  {
    int row = tid >> 4, q0 = (tid & 15) * 8;
    const float* sp = prevz + (size_t)(g * 16 + row) * 128 + q0;
    float4 a = *(const float4*)sp;
    float4 b = *(const float4*)(sp + 4);
    *(uint4*)(&zl[row * 136 + SWC(row, q0)]) =
        make_uint4(pk2(a.x, a.y), pk2(a.z, a.w), pk2(b.x, b.y), pk2(b.z, b.w));
  }
  const uint4* cqp = (const uint4*)cq + ((size_t)g * 256) * 512 + (size_t)tid * 2;
  uint4 cb0 = cqp[0], cb1 = cqp[1];
  __syncthreads();

  for (int s = 0; s < 256; ++s) {
    // unpack Cq into L1 accumulators
    facc4 a[4];
    a[0][0] = bf2f(cb0.x & 0xffffu); a[0][1] = bf2f(cb0.x >> 16);
    a[0][2] = bf2f(cb0.y & 0xffffu); a[0][3] = bf2f(cb0.y >> 16);
    a[2][0] = bf2f(cb0.z & 0xffffu); a[2][1] = bf2f(cb0.z >> 16);
    a[2][2] = bf2f(cb0.w & 0xffffu); a[2][3] = bf2f(cb0.w >> 16);
    a[1][0] = bf2f(cb1.x & 0xffffu); a[1][1] = bf2f(cb1.x >> 16);
    a[1][2] = bf2f(cb1.y & 0xffffu); a[1][3] = bf2f(cb1.y >> 16);
    a[3][0] = bf2f(cb1.z & 0xffffu); a[3][1] = bf2f(cb1.z >> 16);
    a[3][2] = bf2f(cb1.w & 0xffffu); a[3][3] = bf2f(cb1.w >> 16);
    // prefetch next-step Cq; load this step's eps (used only at epilogue)
    const int sn = (s + 1 < 256) ? s + 1 : s;
    const uint4 nb0 = cqp[(size_t)sn * 512], nb1 = cqp[(size_t)sn * 512 + 1];
    float ep0[4], ep1[4];
#pragma unroll
    for (int i = 0; i < 4; ++i) {
      size_t eb = ((size_t)(g * 16 + rr + i) * 256 + s) * 128;
      ep0[i] = eps[eb + c0];
      ep1[i] = eps[eb + c1];
    }
    // ---- layer 1: relu(Cq + z @ Uq) ----
#pragma unroll
    for (int kt = 0; kt < 4; ++kt) {
      bfrag8 zf = *(const bfrag8*)(&zl[lm * 136 + SWC(lm, kt * 32 + lg * 8)]);
#pragma unroll
      for (int j = 0; j < 4; ++j) a[j] = mfma_bf16(zf, u[j][kt], a[j]);
    }
#pragma unroll
    for (int j = 0; j < 4; ++j)
#pragma unroll
      for (int i = 0; i < 4; ++i)
        h1[(rr + i) * 264 + SWC(rr + i, cc[j])] = f2bf(fmaxf(a[j][i], 0.f));
    wg_barrier();
    // ---- layer 2 ----
    facc4 c[4];
#pragma unroll
    for (int j = 0; j < 4; ++j) c[j] = (facc4){b2[j], b2[j], b2[j], b2[j]};
#pragma unroll
    for (int kt = 0; kt < 8; ++kt) {
      bfrag8 hf = *(const bfrag8*)(&h1[lm * 264 + SWC(lm, kt * 32 + lg * 8)]);
#pragma unroll
      for (int j = 0; j < 4; ++j) c[j] = mfma_bf16(hf, w2[j][kt], c[j]);
    }
#pragma unroll
    for (int j = 0; j < 4; ++j)
#pragma unroll
      for (int i = 0; i < 4; ++i)
        h2[(rr + i) * 264 + SWC(rr + i, cc[j])] = f2bf(fmaxf(c[j][i], 0.f));
    wg_barrier();
    // ---- layer 3 (linear) + reparameterization, in-lane ----
    facc4 o[4];
#pragma unroll
    for (int j = 0; j < 4; ++j) o[j] = (facc4){b3[j], b3[j], b3[j], b3[j]};
#pragma unroll
    for (int kt = 0; kt < 8; ++kt) {
      bfrag8 hf = *(const bfrag8*)(&h2[lm * 264 + SWC(lm, kt * 32 + lg * 8)]);
#pragma unroll
      for (int j = 0; j < 4; ++j) o[j] = mfma_bf16(hf, w3[j][kt], o[j]);
    }
#pragma unroll
    for (int i = 0; i < 4; ++i) {
      size_t ob = ((size_t)(g * 16 + rr + i) * 256 + s) * 128;
      float zq0 = o[0][i] + ep0[i] * __expf(0.5f * o[2][i]);
      float zq1 = o[1][i] + ep1[i] * __expf(0.5f * o[3][i]);
      qm_o[ob + c0]  = o[0][i];  qm_o[ob + c1]  = o[1][i];
      qlv_o[ob + c0] = o[2][i];  qlv_o[ob + c1] = o[3][i];
      z_o[ob + c0]   = zq0;      z_o[ob + c1]   = zq1;
      zl[(rr + i) * 136 + SWC(rr + i, c0)] = f2bf(zq0);
      zl[(rr + i) * 136 + SWC(rr + i, c1)] = f2bf(zq1);
    }
    wg_barrier();
    cb0 = nb0; cb1 = nb1;
  }
}

// ---------------------------------------------------------------------------
// K3: prior MLP. 256 thr (4 waves), M=64 batch rows, one s. grid = 16*256.
// ---------------------------------------------------------------------------
__global__ __launch_bounds__(256, 2) void k3_prior(
    const float* __restrict__ prevz, const float* __restrict__ z_in,
    const unsigned short* __restrict__ cp,
    const unsigned short* __restrict__ wU, const unsigned short* __restrict__ w2p,
    const unsigned short* __restrict__ w3p,
    const float* __restrict__ pb1, const float* __restrict__ pb2,
    const float* __restrict__ pb3,
    float* __restrict__ pm_o, float* __restrict__ plv_o) {
  __shared__ unsigned short zl[64 * 136];
  __shared__ unsigned short hb[64 * 264];
  const int bid = blockIdx.x;
  const int gp = bid >> 8, s = bid & 255;
  const int tid = threadIdx.x;
  const int w = tid >> 6, l = tid & 63, lm = l & 15, lg = l >> 4;
  const int rr = lg * 4;
  const int nt[4] = {2 * w, 2 * w + 1, 2 * w + 8, 2 * w + 9};
  const int c0 = 32 * w + lm, c1 = c0 + 16;
  const int cc[4] = {c0, c1, 128 + c0, 128 + c1};
  {
    int row = tid >> 2, q0 = (tid & 3) * 32;
    const float* sp = (s == 0) ? (prevz + (size_t)(gp * 64 + row) * 128 + q0)
                               : (z_in + ((size_t)(gp * 64 + row) * 256 + (s - 1)) * 128 + q0);
#pragma unroll
    for (int q = 0; q < 4; ++q) {
      float4 a = *(const float4*)(sp + q * 8);
      float4 b = *(const float4*)(sp + q * 8 + 4);
      *(uint4*)(&zl[row * 136 + SWC(row, q0 + q * 8)]) =
          make_uint4(pk2(a.x, a.y), pk2(a.z, a.w), pk2(b.x, b.y), pk2(b.z, b.w));
    }
  }
  const float pb[4] = {pb1[nt[0] * 16 + lm], pb1[nt[1] * 16 + lm],
                       pb1[nt[2] * 16 + lm], pb1[nt[3] * 16 + lm]};
  facc4 acc[4][4];
#pragma unroll
  for (int rt = 0; rt < 4; ++rt)
#pragma unroll
    for (int i = 0; i < 4; ++i) {
      int b = gp * 64 + rt * 16 + rr + i;
      uint2 v = ((const uint2*)cp)[((size_t)b * 256 + s) * 64 + w * 16 + lm];
      acc[rt][0][i] = pb[0] + bf2f(v.x & 0xffffu);
      acc[rt][1][i] = pb[1] + bf2f(v.x >> 16);
      acc[rt][2][i] = pb[2] + bf2f(v.y & 0xffffu);
      acc[rt][3][i] = pb[3] + bf2f(v.y >> 16);
    }
  __syncthreads();
  // ---- layer 1: + z @ Up ----
#pragma unroll
  for (int kt = 0; kt < 4; ++kt) {
    bfrag8 b0 = *(const bfrag8*)(wU + ((size_t)(nt[0] * 4 + kt) * 64 + l) * 8);
    bfrag8 b1 = *(const bfrag8*)(wU + ((size_t)(nt[1] * 4 + kt) * 64 + l) * 8);
    bfrag8 b2f = *(const bfrag8*)(wU + ((size_t)(nt[2] * 4 + kt) * 64 + l) * 8);
    bfrag8 b3f = *(const bfrag8*)(wU + ((size_t)(nt[3] * 4 + kt) * 64 + l) * 8);
#pragma unroll
    for (int rt = 0; rt < 4; ++rt) {
      bfrag8 zf = *(const bfrag8*)(&zl[(rt * 16 + lm) * 136 + SWC(lm, kt * 32 + lg * 8)]);
      acc[rt][0] = mfma_bf16(zf, b0, acc[rt][0]);
      acc[rt][1] = mfma_bf16(zf, b1, acc[rt][1]);
      acc[rt][2] = mfma_bf16(zf, b2f, acc[rt][2]);
      acc[rt][3] = mfma_bf16(zf, b3f, acc[rt][3]);
    }
  }
#pragma unroll
  for (int rt = 0; rt < 4; ++rt)
#pragma unroll
    for (int j = 0; j < 4; ++j)
#pragma unroll
      for (int i = 0; i < 4; ++i) {
        int r = rt * 16 + rr + i;
        hb[r * 264 + SWC(r, cc[j])] = f2bf(fmaxf(acc[rt][j][i], 0.f));
      }
  __syncthreads();
  // ---- layer 2 ----
  facc4 a2[4][4];
#pragma unroll
  for (int rt = 0; rt < 4; ++rt)
#pragma unroll
    for (int j = 0; j < 4; ++j) a2[rt][j] = (facc4){pb2[nt[j] * 16 + lm], pb2[nt[j] * 16 + lm],
                                                    pb2[nt[j] * 16 + lm], pb2[nt[j] * 16 + lm]};
#pragma unroll
  for (int kt = 0; kt < 8; ++kt) {
    bfrag8 b0 = *(const bfrag8*)(w2p + ((size_t)(nt[0] * 8 + kt) * 64 + l) * 8);
    bfrag8 b1 = *(const bfrag8*)(w2p + ((size_t)(nt[1] * 8 + kt) * 64 + l) * 8);
    bfrag8 b2f = *(const bfrag8*)(w2p + ((size_t)(nt[2] * 8 + kt) * 64 + l) * 8);
    bfrag8 b3f = *(const bfrag8*)(w2p + ((size_t)(nt[3] * 8 + kt) * 64 + l) * 8);
#pragma unroll
    for (int rt = 0; rt < 4; ++rt) {
      bfrag8 hf = *(const bfrag8*)(&hb[(rt * 16 + lm) * 264 + SWC(lm, kt * 32 + lg * 8)]);
      a2[rt][0] = mfma_bf16(hf, b0, a2[rt][0]);
      a2[rt][1] = mfma_bf16(hf, b1, a2[rt][1]);
      a2[rt][2] = mfma_bf16(hf, b2f, a2[rt][2]);
      a2[rt][3] = mfma_bf16(hf, b3f, a2[rt][3]);
    }
  }
  __syncthreads();   // all h1 reads complete before overwrite
#pragma unroll
  for (int rt = 0; rt < 4; ++rt)
#pragma unroll
    for (int j = 0; j < 4; ++j)
#pragma unroll
      for (int i = 0; i < 4; ++i) {
        int r = rt * 16 + rr + i;
        hb[r * 264 + SWC(r, cc[j])] = f2bf(fmaxf(a2[rt][j][i], 0.f));
      }
  __syncthreads();
  // ---- layer 3 (linear) ----
  facc4 a3[4][4];
#pragma unroll
  for (int rt = 0; rt < 4; ++rt)
#pragma unroll
    for (int j = 0; j < 4; ++j) a3[rt][j] = (facc4){pb3[nt[j] * 16 + lm], pb3[nt[j] * 16 + lm],
                                                    pb3[nt[j] * 16 + lm], pb3[nt[j] * 16 + lm]};
#pragma unroll
  for (int kt = 0; kt < 8; ++kt) {
    bfrag8 b0 = *(const bfrag8*)(w3p + ((size_t)(nt[0] * 8 + kt) * 64 + l) * 8);
    bfrag8 b1 = *(const bfrag8*)(w3p + ((size_t)(nt[1] * 8 + kt) * 64 + l) * 8);
    bfrag8 b2f = *(const bfrag8*)(w3p + ((size_t)(nt[2] * 8 + kt) * 64 + l) * 8);
    bfrag8 b3f = *(const bfrag8*)(w3p + ((size_t)(nt[3] * 8 + kt) * 64 + l) * 8);
#pragma unroll
    for (int rt = 0; rt < 4; ++rt) {
      bfrag8 hf = *(const bfrag8*)(&hb[(rt * 16 + lm) * 264 + SWC(lm, kt * 32 + lg * 8)]);
      a3[rt][0] = mfma_bf16(hf, b0, a3[rt][0]);
      a3[rt][1] = mfma_bf16(hf, b1, a3[rt][1]);
      a3[rt][2] = mfma_bf16(hf, b2f, a3[rt][2]);
      a3[rt][3] = mfma_bf16(hf, b3f, a3[rt][3]);
    }
  }
#pragma unroll
  for (int rt = 0; rt < 4; ++rt)
#pragma unroll
    for (int i = 0; i < 4; ++i) {
      size_t base = ((size_t)(gp * 64 + rt * 16 + rr + i) * 256 + s) * 128;
      pm_o[base + c0]  = a3[rt][0][i];
      pm_o[base + c1]  = a3[rt][1][i];
      plv_o[base + c0] = a3[rt][2][i];
      plv_o[base + c1] = a3[rt][3][i];
    }
}

// ---------------------------------------------------------------------------
extern "C" void kernel_launch(void* const* d_in, const int* in_sizes, int n_in,
                              void* d_out, int out_size, void* d_ws, size_t ws_size,
                              hipStream_t stream) {
  const float* enc   = (const float*)d_in[0];
  const float* prevz = (const float*)d_in[1];
  const float* eps   = (const float*)d_in[2];
  const float* pW1 = (const float*)d_in[3];
  const float* pb1 = (const float*)d_in[4];
  const float* pW2 = (const float*)d_in[5];
  const float* pb2 = (const float*)d_in[6];
  const float* pW3 = (const float*)d_in[7];
  const float* pb3 = (const float*)d_in[8];
  const float* qW1 = (const float*)d_in[9];
  const float* qb1 = (const float*)d_in[10];
  const float* qW2 = (const float*)d_in[11];
  const float* qb2 = (const float*)d_in[12];
  const float* qW3 = (const float*)d_in[13];
  const float* qb3 = (const float*)d_in[14];

  float* out = (float*)d_out;
  const size_t O = (size_t)1024 * 256 * 128;
  float* z_o   = out;
  float* pm_o  = out + O;
  float* plv_o = out + 2 * O;
  float* qm_o  = out + 3 * O;
  float* qlv_o = out + 4 * O;
  unsigned short* cq = (unsigned short*)pm_o;   // frag-packed Cq (k2 input)
  unsigned short* cp = (unsigned short*)plv_o;  // slot-packed Cp (k3 input)

  unsigned short* ws = (unsigned short*)d_ws;
  unsigned short* Wqe  = ws;             // 65536
  unsigned short* Uq   = ws + 65536;     // 32768
  unsigned short* W2q  = ws + 98304;     // 65536
  unsigned short* W3q  = ws + 163840;    // 65536
  unsigned short* W1ph = ws + 229376;    // 65536
  unsigned short* Up   = ws + 294912;    // 32768
  unsigned short* W2p  = ws + 327680;    // 65536
  unsigned short* W3p  = ws + 393216;    // 65536

  pack_all<<<224, 256, 0, stream>>>(qW1, qW2, qW3, pW1, pW2, pW3, ws);
  k1_pre<<<8192, 256, 0, stream>>>(enc, Wqe, W1ph, qb1, cq, cp);
  k2_scan<<<64, 256, 0, stream>>>(prevz, eps, Uq, W2q, W3q, qb2, qb3, cq,
                                  z_o, qm_o, qlv_o);
  k3_prior<<<4096, 256, 0, stream>>>(prevz, z_o, cp, Up, W2p, W3p,
                                     pb1, pb2, pb3, pm_o, plv_o);
}

// Round 5
// 755.793 us; speedup vs baseline: 1.2831x; 1.2831x over previous
//
#include <hip/hip_runtime.h>

// ---------------------------------------------------------------------------
// ConditionalVariationalModule: B=1024, S=256, INPUT=256, LATENT=128, HIDDEN=256
//   K1: Cq = h@(qW1[0:256]+qW1[384:640]) + qb1  -> frag-packed bf16 in pm region
//       Cp = h@pW1[0:256]                       -> slot-packed bf16 in plv region
//   K2: sequential posterior scan, 64 WGs x 16 rows, 8 waves x 2 n-tiles
//       (nt = {w, w+8} so each lane owns qm[c] AND qlv[c] -> in-lane z),
//       weights VGPR-resident (160 regs, fits 256 cap), raw barriers.
//   K3: prior MLP (z@Up + Cp -> L2 -> L3), 4 waves, M=64 batch rows, one s.
// Outputs (fp32): z | pm | plv | qm | qlv, each [B,S,128].
// ---------------------------------------------------------------------------

typedef __attribute__((ext_vector_type(8))) short bfrag8;   // 8 bf16 = 4 VGPR
typedef __attribute__((ext_vector_type(4))) float facc4;    // MFMA accum
typedef __attribute__((ext_vector_type(4))) unsigned int u32x4;

__device__ __forceinline__ unsigned short f2bf(float x) {
  unsigned int u = __float_as_uint(x);
  u = (u + 0x7fffu + ((u >> 16) & 1u)) >> 16;   // RNE
  return (unsigned short)u;
}
__device__ __forceinline__ unsigned int pk2(float a, float b) {
  return (unsigned int)f2bf(a) | ((unsigned int)f2bf(b) << 16);
}
__device__ __forceinline__ float bf2f(unsigned int lo) {
  return __uint_as_float(lo << 16);
}
__device__ __forceinline__ facc4 mfma_bf16(bfrag8 a, bfrag8 b, facc4 c) {
  return __builtin_amdgcn_mfma_f32_16x16x32_bf16(a, b, c, 0, 0, 0);
}
// Load a B-fragment as an opaque register value (cannot be rematerialized).
__device__ __forceinline__ bfrag8 load_pin(const unsigned short* p) {
  u32x4 v = *(const u32x4*)p;
  asm volatile("" : "+v"(v));
  return __builtin_bit_cast(bfrag8, v);
}
// raw workgroup barrier: LDS ordering only, NO vmcnt(0) drain
__device__ __forceinline__ void wg_barrier() {
  asm volatile("s_waitcnt lgkmcnt(0)" ::: "memory");
  __builtin_amdgcn_sched_barrier(0);
  __builtin_amdgcn_s_barrier();
  __builtin_amdgcn_sched_barrier(0);
}
#define SWC(r, c) ((c) ^ (((r) & 8) << 1))

// ---------------------------------------------------------------------------
// Pack all 8 weight matrices into B-fragment order:
// dst[((nt*KT+kt)*64+l)*8+i] = bf16( W[kt*32+(l>>4)*8+i][nt*16+(l&15)] )
// ---------------------------------------------------------------------------
__global__ void pack_all(const float* __restrict__ qW1, const float* __restrict__ qW2,
                         const float* __restrict__ qW3, const float* __restrict__ pW1,
                         const float* __restrict__ pW2, const float* __restrict__ pW3,
                         unsigned short* __restrict__ ws) {
  int b = blockIdx.x;
  const float* src; const float* src2 = nullptr; unsigned short* dst; int KT;
  if (b < 32)       { src = qW1; src2 = qW1 + 384 * 256; dst = ws;          KT = 8; }
  else if (b < 48)  { b -= 32;  src = qW1 + 256 * 256;   dst = ws + 65536;  KT = 4; }
  else if (b < 80)  { b -= 48;  src = qW2;               dst = ws + 98304;  KT = 8; }
  else if (b < 112) { b -= 80;  src = qW3;               dst = ws + 163840; KT = 8; }
  else if (b < 144) { b -= 112; src = pW1;               dst = ws + 229376; KT = 8; }
  else if (b < 160) { b -= 144; src = pW1 + 256 * 256;   dst = ws + 294912; KT = 4; }
  else if (b < 192) { b -= 160; src = pW2;               dst = ws + 327680; KT = 8; }
  else              { b -= 192; src = pW3;               dst = ws + 393216; KT = 8; }
  int t = b * 256 + (int)threadIdx.x;
  if (t >= 16 * KT * 64) return;
  int l  = t & 63;
  int kt = (t >> 6) % KT;
  int nt = t / (64 * KT);
  int n  = nt * 16 + (l & 15);
  int k0 = kt * 32 + (l >> 4) * 8;
  unsigned int o[4];
#pragma unroll
  for (int p = 0; p < 4; ++p) {
    float a = src[(size_t)(k0 + 2 * p) * 256 + n];
    float c = src[(size_t)(k0 + 2 * p + 1) * 256 + n];
    if (src2) {
      a += src2[(size_t)(k0 + 2 * p) * 256 + n];
      c += src2[(size_t)(k0 + 2 * p + 1) * 256 + n];
    }
    o[p] = pk2(a, c);
  }
  *(uint4*)(dst + (size_t)t * 8) = make_uint4(o[0], o[1], o[2], o[3]);
}

// ---------------------------------------------------------------------------
// K1: Cq (frag-packed for k2) + Cp (slot-packed for k3). 256 thr, M=32.
// ---------------------------------------------------------------------------
__global__ __launch_bounds__(256, 2) void k1_pre(
    const float* __restrict__ enc, const unsigned short* __restrict__ wq,
    const unsigned short* __restrict__ wp, const float* __restrict__ qb1,
    unsigned short* __restrict__ cq, unsigned short* __restrict__ cp) {
  __shared__ unsigned short xl[32 * 264];
  const int bid = blockIdx.x;
  const int gp = bid >> 8, s = bid & 255;
  const int tid = threadIdx.x;
  {
    int row = tid >> 3, c0 = (tid & 7) * 32;
    const float* sp = enc + (((size_t)(gp * 32 + row) * 256 + s) * 256 + c0);
#pragma unroll
    for (int q = 0; q < 4; ++q) {
      float4 a = *(const float4*)(sp + q * 8);
      float4 b = *(const float4*)(sp + q * 8 + 4);
      *(uint4*)(&xl[row * 264 + SWC(row, c0 + q * 8)]) =
          make_uint4(pk2(a.x, a.y), pk2(a.z, a.w), pk2(b.x, b.y), pk2(b.z, b.w));
    }
  }
  __syncthreads();
  const int w = tid >> 6, l = tid & 63, lm = l & 15, lg = l >> 4;
  const int rr = lg * 4;
  const int nt[4] = {2 * w, 2 * w + 1, 2 * w + 8, 2 * w + 9};
  facc4 aq[2][4], ap[2][4];
#pragma unroll
  for (int j = 0; j < 4; ++j) {
    float bv = qb1[nt[j] * 16 + lm];
    aq[0][j] = (facc4){bv, bv, bv, bv}; aq[1][j] = aq[0][j];
    ap[0][j] = (facc4){0.f, 0.f, 0.f, 0.f}; ap[1][j] = ap[0][j];
  }
#pragma unroll
  for (int kt = 0; kt < 8; ++kt) {
    bfrag8 bq[4], bp[4];
#pragma unroll
    for (int j = 0; j < 4; ++j) {
      bq[j] = *(const bfrag8*)(wq + ((size_t)(nt[j] * 8 + kt) * 64 + l) * 8);
      bp[j] = *(const bfrag8*)(wp + ((size_t)(nt[j] * 8 + kt) * 64 + l) * 8);
    }
#pragma unroll
    for (int rt = 0; rt < 2; ++rt) {
      bfrag8 x = *(const bfrag8*)(&xl[(rt * 16 + lm) * 264 + SWC(lm, kt * 32 + lg * 8)]);
#pragma unroll
      for (int j = 0; j < 4; ++j) {
        aq[rt][j] = mfma_bf16(x, bq[j], aq[rt][j]);
        ap[rt][j] = mfma_bf16(x, bp[j], ap[rt][j]);
      }
    }
  }
#pragma unroll
  for (int rt = 0; rt < 2; ++rt) {
    size_t base = ((size_t)((gp * 2 + rt) * 256 + s)) * 512 + (size_t)tid * 2;
    ((uint4*)cq)[base + 0] =
        make_uint4(pk2(aq[rt][0][0], aq[rt][0][1]), pk2(aq[rt][0][2], aq[rt][0][3]),
                   pk2(aq[rt][2][0], aq[rt][2][1]), pk2(aq[rt][2][2], aq[rt][2][3]));
    ((uint4*)cq)[base + 1] =
        make_uint4(pk2(aq[rt][1][0], aq[rt][1][1]), pk2(aq[rt][1][2], aq[rt][1][3]),
                   pk2(aq[rt][3][0], aq[rt][3][1]), pk2(aq[rt][3][2], aq[rt][3][3]));
#pragma unroll
    for (int i = 0; i < 4; ++i) {
      int b = gp * 32 + rt * 16 + rr + i;
      ((uint2*)cp)[((size_t)b * 256 + s) * 64 + w * 16 + lm] =
          make_uint2(pk2(ap[rt][0][i], ap[rt][1][i]), pk2(ap[rt][2][i], ap[rt][3][i]));
    }
  }
}

// ---------------------------------------------------------------------------
// K2: sequential posterior scan. 64 WGs x 512 thr (8 waves, 2/SIMD).
// Wave w owns nt {w, w+8}: lane (w,lm) holds qm col c=16w+lm AND qlv col c
// -> z fully in-lane. Weights: 40 frags = 160 VGPR, pinned (fits 256 cap).
// cq: one uint4/lane/step (k1 pair layout co-locates nt w and w+8).
// ---------------------------------------------------------------------------
__global__ __launch_bounds__(512, 2) void k2_scan(
    const float* __restrict__ prevz, const float* __restrict__ eps,
    const unsigned short* __restrict__ wU, const unsigned short* __restrict__ wW2,
    const unsigned short* __restrict__ wW3,
    const float* __restrict__ qb2, const float* __restrict__ qb3,
    const unsigned short* __restrict__ cq,
    float* __restrict__ z_o, float* __restrict__ qm_o, float* __restrict__ qlv_o) {
  __shared__ unsigned short zl[16 * 136];
  __shared__ unsigned short h1[16 * 264];
  __shared__ unsigned short h2[16 * 264];
  const int g = blockIdx.x, tid = threadIdx.x;
  const int w = tid >> 6, l = tid & 63, lm = l & 15, lg = l >> 4;
  const int rr = lg * 4;
  const int c = 16 * w + lm;            // qm col = qlv col
  const int cc[2] = {c, 128 + c};       // h cols for nt w, w+8

  bfrag8 u[2][4], w2[2][8], w3[2][8];
#pragma unroll
  for (int j = 0; j < 2; ++j) {
    const int nt = w + 8 * j;
#pragma unroll
    for (int kt = 0; kt < 4; ++kt)
      u[j][kt] = load_pin(wU + ((size_t)(nt * 4 + kt) * 64 + l) * 8);
#pragma unroll
    for (int kt = 0; kt < 8; ++kt) {
      w2[j][kt] = load_pin(wW2 + ((size_t)(nt * 8 + kt) * 64 + l) * 8);
      w3[j][kt] = load_pin(wW3 + ((size_t)(nt * 8 + kt) * 64 + l) * 8);
    }
  }
  const float b2[2] = {qb2[c], qb2[128 + c]};
  const float b3[2] = {qb3[c], qb3[128 + c]};
  {
    int row = tid >> 5, q0 = (tid & 31) * 4;
    float4 v = *(const float4*)(prevz + (size_t)(g * 16 + row) * 128 + q0);
    *(uint2*)(&zl[row * 136 + SWC(row, q0)]) = make_uint2(pk2(v.x, v.y), pk2(v.z, v.w));
  }
  // cq: pair word (w>>1)*64+l, half w&1 holds (nt w, nt w+8) fragments
  const uint4* cqp = (const uint4*)cq + ((size_t)g * 256) * 512 +
                     (size_t)((w >> 1) * 64 + l) * 2 + (w & 1);
  uint4 cb = cqp[0];
  float ep[4];
#pragma unroll
  for (int i = 0; i < 4; ++i)
    ep[i] = eps[((size_t)(g * 16 + rr + i) * 256) * 128 + c];
  __syncthreads();

  for (int s = 0; s < 256; ++s) {
    // unpack Cq: x,y = qm-nt acc, z,w = qlv-nt acc
    facc4 a[2];
    a[0][0] = bf2f(cb.x & 0xffffu); a[0][1] = bf2f(cb.x >> 16);
    a[0][2] = bf2f(cb.y & 0xffffu); a[0][3] = bf2f(cb.y >> 16);
    a[1][0] = bf2f(cb.z & 0xffffu); a[1][1] = bf2f(cb.z >> 16);
    a[1][2] = bf2f(cb.w & 0xffffu); a[1][3] = bf2f(cb.w >> 16);
    // prefetch next-step Cq and eps
    const int sn = (s + 1 < 256) ? s + 1 : s;
    const uint4 nb = cqp[(size_t)sn * 512];
    float epn[4];
#pragma unroll
    for (int i = 0; i < 4; ++i)
      epn[i] = eps[((size_t)(g * 16 + rr + i) * 256 + sn) * 128 + c];
    // ---- layer 1: relu(Cq + z @ Uq) ----
#pragma unroll
    for (int kt = 0; kt < 4; ++kt) {
      bfrag8 zf = *(const bfrag8*)(&zl[lm * 136 + SWC(lm, kt * 32 + lg * 8)]);
      a[0] = mfma_bf16(zf, u[0][kt], a[0]);
      a[1] = mfma_bf16(zf, u[1][kt], a[1]);
    }
#pragma unroll
    for (int j = 0; j < 2; ++j)
#pragma unroll
      for (int i = 0; i < 4; ++i)
        h1[(rr + i) * 264 + SWC(rr + i, cc[j])] = f2bf(fmaxf(a[j][i], 0.f));
    wg_barrier();
    // ---- layer 2 ----
    facc4 cv[2] = {(facc4){b2[0], b2[0], b2[0], b2[0]},
                   (facc4){b2[1], b2[1], b2[1], b2[1]}};
#pragma unroll
    for (int kt = 0; kt < 8; ++kt) {
      bfrag8 hf = *(const bfrag8*)(&h1[lm * 264 + SWC(lm, kt * 32 + lg * 8)]);
      cv[0] = mfma_bf16(hf, w2[0][kt], cv[0]);
      cv[1] = mfma_bf16(hf, w2[1][kt], cv[1]);
    }
#pragma unroll
    for (int j = 0; j < 2; ++j)
#pragma unroll
      for (int i = 0; i < 4; ++i)
        h2[(rr + i) * 264 + SWC(rr + i, cc[j])] = f2bf(fmaxf(cv[j][i], 0.f));
    wg_barrier();
    // ---- layer 3 (linear) + reparameterization, in-lane ----
    facc4 o[2] = {(facc4){b3[0], b3[0], b3[0], b3[0]},
                  (facc4){b3[1], b3[1], b3[1], b3[1]}};
#pragma unroll
    for (int kt = 0; kt < 8; ++kt) {
      bfrag8 hf = *(const bfrag8*)(&h2[lm * 264 + SWC(lm, kt * 32 + lg * 8)]);
      o[0] = mfma_bf16(hf, w3[0][kt], o[0]);
      o[1] = mfma_bf16(hf, w3[1][kt], o[1]);
    }
#pragma unroll
    for (int i = 0; i < 4; ++i) {
      size_t ob = ((size_t)(g * 16 + rr + i) * 256 + s) * 128;
      float zq = o[0][i] + ep[i] * __expf(0.5f * o[1][i]);
      qm_o[ob + c]  = o[0][i];
      qlv_o[ob + c] = o[1][i];
      z_o[ob + c]   = zq;
      zl[(rr + i) * 136 + SWC(rr + i, c)] = f2bf(zq);
    }
    wg_barrier();
    cb = nb;
#pragma unroll
    for (int i = 0; i < 4; ++i) ep[i] = epn[i];
  }
}

// ---------------------------------------------------------------------------
// K3: prior MLP. 256 thr (4 waves), M=64 batch rows, one s. grid = 16*256.
// ---------------------------------------------------------------------------
__global__ __launch_bounds__(256, 2) void k3_prior(
    const float* __restrict__ prevz, const float* __restrict__ z_in,
    const unsigned short* __restrict__ cp,
    const unsigned short* __restrict__ wU, const unsigned short* __restrict__ w2p,
    const unsigned short* __restrict__ w3p,
    const float* __restrict__ pb1, const float* __restrict__ pb2,
    const float* __restrict__ pb3,
    float* __restrict__ pm_o, float* __restrict__ plv_o) {
  __shared__ unsigned short zl[64 * 136];
  __shared__ unsigned short hb[64 * 264];
  const int bid = blockIdx.x;
  const int gp = bid >> 8, s = bid & 255;
  const int tid = threadIdx.x;
  const int w = tid >> 6, l = tid & 63, lm = l & 15, lg = l >> 4;
  const int rr = lg * 4;
  const int nt[4] = {2 * w, 2 * w + 1, 2 * w + 8, 2 * w + 9};
  const int c0 = 32 * w + lm, c1 = c0 + 16;
  const int cc[4] = {c0, c1, 128 + c0, 128 + c1};
  {
    int row = tid >> 2, q0 = (tid & 3) * 32;
    const float* sp = (s == 0) ? (prevz + (size_t)(gp * 64 + row) * 128 + q0)
                               : (z_in + ((size_t)(gp * 64 + row) * 256 + (s - 1)) * 128 + q0);
#pragma unroll
    for (int q = 0; q < 4; ++q) {
      float4 a = *(const float4*)(sp + q * 8);
      float4 b = *(const float4*)(sp + q * 8 + 4);
      *(uint4*)(&zl[row * 136 + SWC(row, q0 + q * 8)]) =
          make_uint4(pk2(a.x, a.y), pk2(a.z, a.w), pk2(b.x, b.y), pk2(b.z, b.w));
    }
  }
  const float pb[4] = {pb1[nt[0] * 16 + lm], pb1[nt[1] * 16 + lm],
                       pb1[nt[2] * 16 + lm], pb1[nt[3] * 16 + lm]};
  facc4 acc[4][4];
#pragma unroll
  for (int rt = 0; rt < 4; ++rt)
#pragma unroll
    for (int i = 0; i < 4; ++i) {
      int b = gp * 64 + rt * 16 + rr + i;
      uint2 v = ((const uint2*)cp)[((size_t)b * 256 + s) * 64 + w * 16 + lm];
      acc[rt][0][i] = pb[0] + bf2f(v.x & 0xffffu);
      acc[rt][1][i] = pb[1] + bf2f(v.x >> 16);
      acc[rt][2][i] = pb[2] + bf2f(v.y & 0xffffu);
      acc[rt][3][i] = pb[3] + bf2f(v.y >> 16);
    }
  __syncthreads();
  // ---- layer 1: + z @ Up ----
#pragma unroll
  for (int kt = 0; kt < 4; ++kt) {
    bfrag8 b0 = *(const bfrag8*)(wU + ((size_t)(nt[0] * 4 + kt) * 64 + l) * 8);
    bfrag8 b1 = *(const bfrag8*)(wU + ((size_t)(nt[1] * 4 + kt) * 64 + l) * 8);
    bfrag8 b2f = *(const bfrag8*)(wU + ((size_t)(nt[2] * 4 + kt) * 64 + l) * 8);
    bfrag8 b3f = *(const bfrag8*)(wU + ((size_t)(nt[3] * 4 + kt) * 64 + l) * 8);
#pragma unroll
    for (int rt = 0; rt < 4; ++rt) {
      bfrag8 zf = *(const bfrag8*)(&zl[(rt * 16 + lm) * 136 + SWC(lm, kt * 32 + lg * 8)]);
      acc[rt][0] = mfma_bf16(zf, b0, acc[rt][0]);
      acc[rt][1] = mfma_bf16(zf, b1, acc[rt][1]);
      acc[rt][2] = mfma_bf16(zf, b2f, acc[rt][2]);
      acc[rt][3] = mfma_bf16(zf, b3f, acc[rt][3]);
    }
  }
#pragma unroll
  for (int rt = 0; rt < 4; ++rt)
#pragma unroll
    for (int j = 0; j < 4; ++j)
#pragma unroll
      for (int i = 0; i < 4; ++i) {
        int r = rt * 16 + rr + i;
        hb[r * 264 + SWC(r, cc[j])] = f2bf(fmaxf(acc[rt][j][i], 0.f));
      }
  __syncthreads();
  // ---- layer 2 ----
  facc4 a2[4][4];
#pragma unroll
  for (int rt = 0; rt < 4; ++rt)
#pragma unroll
    for (int j = 0; j < 4; ++j) a2[rt][j] = (facc4){pb2[nt[j] * 16 + lm], pb2[nt[j] * 16 + lm],
                                                    pb2[nt[j] * 16 + lm], pb2[nt[j] * 16 + lm]};
#pragma unroll
  for (int kt = 0; kt < 8; ++kt) {
    bfrag8 b0 = *(const bfrag8*)(w2p + ((size_t)(nt[0] * 8 + kt) * 64 + l) * 8);
    bfrag8 b1 = *(const bfrag8*)(w2p + ((size_t)(nt[1] * 8 + kt) * 64 + l) * 8);
    bfrag8 b2f = *(const bfrag8*)(w2p + ((size_t)(nt[2] * 8 + kt) * 64 + l) * 8);
    bfrag8 b3f = *(const bfrag8*)(w2p + ((size_t)(nt[3] * 8 + kt) * 64 + l) * 8);
#pragma unroll
    for (int rt = 0; rt < 4; ++rt) {
      bfrag8 hf = *(const bfrag8*)(&hb[(rt * 16 + lm) * 264 + SWC(lm, kt * 32 + lg * 8)]);
      a2[rt][0] = mfma_bf16(hf, b0, a2[rt][0]);
      a2[rt][1] = mfma_bf16(hf, b1, a2[rt][1]);
      a2[rt][2] = mfma_bf16(hf, b2f, a2[rt][2]);
      a2[rt][3] = mfma_bf16(hf, b3f, a2[rt][3]);
    }
  }
  __syncthreads();   // all h1 reads complete before overwrite
#pragma unroll
  for (int rt = 0; rt < 4; ++rt)
#pragma unroll
    for (int j = 0; j < 4; ++j)
#pragma unroll
      for (int i = 0; i < 4; ++i) {
        int r = rt * 16 + rr + i;
        hb[r * 264 + SWC(r, cc[j])] = f2bf(fmaxf(a2[rt][j][i], 0.f));
      }
  __syncthreads();
  // ---- layer 3 (linear) ----
  facc4 a3[4][4];
#pragma unroll
  for (int rt = 0; rt < 4; ++rt)
#pragma unroll
    for (int j = 0; j < 4; ++j) a3[rt][j] = (facc4){pb3[nt[j] * 16 + lm], pb3[nt[j] * 16 + lm],
                                                    pb3[nt[j] * 16 + lm], pb3[nt[j] * 16 + lm]};
#pragma unroll
  for (int kt = 0; kt < 8; ++kt) {
    bfrag8 b0 = *(const bfrag8*)(w3p + ((size_t)(nt[0] * 8 + kt) * 64 + l) * 8);
    bfrag8 b1 = *(const bfrag8*)(w3p + ((size_t)(nt[1] * 8 + kt) * 64 + l) * 8);
    bfrag8 b2f = *(const bfrag8*)(w3p + ((size_t)(nt[2] * 8 + kt) * 64 + l) * 8);
    bfrag8 b3f = *(const bfrag8*)(w3p + ((size_t)(nt[3] * 8 + kt) * 64 + l) * 8);
#pragma unroll
    for (int rt = 0; rt < 4; ++rt) {
      bfrag8 hf = *(const bfrag8*)(&hb[(rt * 16 + lm) * 264 + SWC(lm, kt * 32 + lg * 8)]);
      a3[rt][0] = mfma_bf16(hf, b0, a3[rt][0]);
      a3[rt][1] = mfma_bf16(hf, b1, a3[rt][1]);
      a3[rt][2] = mfma_bf16(hf, b2f, a3[rt][2]);
      a3[rt][3] = mfma_bf16(hf, b3f, a3[rt][3]);
    }
  }
#pragma unroll
  for (int rt = 0; rt < 4; ++rt)
#pragma unroll
    for (int i = 0; i < 4; ++i) {
      size_t base = ((size_t)(gp * 64 + rt * 16 + rr + i) * 256 + s) * 128;
      pm_o[base + c0]  = a3[rt][0][i];
      pm_o[base + c1]  = a3[rt][1][i];
      plv_o[base + c0] = a3[rt][2][i];
      plv_o[base + c1] = a3[rt][3][i];
    }
}

// ---------------------------------------------------------------------------
extern "C" void kernel_launch(void* const* d_in, const int* in_sizes, int n_in,
                              void* d_out, int out_size, void* d_ws, size_t ws_size,
                              hipStream_t stream) {
  const float* enc   = (const float*)d_in[0];
  const float* prevz = (const float*)d_in[1];
  const float* eps   = (const float*)d_in[2];
  const float* pW1 = (const float*)d_in[3];
  const float* pb1 = (const float*)d_in[4];
  const float* pW2 = (const float*)d_in[5];
  const float* pb2 = (const float*)d_in[6];
  const float* pW3 = (const float*)d_in[7];
  const float* pb3 = (const float*)d_in[8];
  const float* qW1 = (const float*)d_in[9];
  const float* qb1 = (const float*)d_in[10];
  const float* qW2 = (const float*)d_in[11];
  const float* qb2 = (const float*)d_in[12];
  const float* qW3 = (const float*)d_in[13];
  const float* qb3 = (const float*)d_in[14];

  float* out = (float*)d_out;
  const size_t O = (size_t)1024 * 256 * 128;
  float* z_o   = out;
  float* pm_o  = out + O;
  float* plv_o = out + 2 * O;
  float* qm_o  = out + 3 * O;
  float* qlv_o = out + 4 * O;
  unsigned short* cq = (unsigned short*)pm_o;   // frag-packed Cq (k2 input)
  unsigned short* cp = (unsigned short*)plv_o;  // slot-packed Cp (k3 input)

  unsigned short* ws = (unsigned short*)d_ws;
  unsigned short* Wqe  = ws;             // 65536
  unsigned short* Uq   = ws + 65536;     // 32768
  unsigned short* W2q  = ws + 98304;     // 65536
  unsigned short* W3q  = ws + 163840;    // 65536
  unsigned short* W1ph = ws + 229376;    // 65536
  unsigned short* Up   = ws + 294912;    // 32768
  unsigned short* W2p  = ws + 327680;    // 65536
  unsigned short* W3p  = ws + 393216;    // 65536

  pack_all<<<224, 256, 0, stream>>>(qW1, qW2, qW3, pW1, pW2, pW3, ws);
  k1_pre<<<8192, 256, 0, stream>>>(enc, Wqe, W1ph, qb1, cq, cp);
  k2_scan<<<64, 512, 0, stream>>>(prevz, eps, Uq, W2q, W3q, qb2, qb3, cq,
                                  z_o, qm_o, qlv_o);
  k3_prior<<<4096, 256, 0, stream>>>(prevz, z_o, cp, Up, W2p, W3p,
                                     pb1, pb2, pb3, pm_o, plv_o);
}